// Round 1
// baseline (758.357 us; speedup 1.0000x reference)
//
#include <hip/hip_runtime.h>

#define NN 40000
#define NE 320000
#define C 256
#define K_ORDER 5

// ---------------- graph preprocessing ----------------

__global__ void count_kernel(const int* __restrict__ ei,
                             int* __restrict__ deg_keep,
                             int* __restrict__ cnt_all) {
    int e = blockIdx.x * 256 + threadIdx.x;
    if (e >= NE) return;
    int r = ei[e];
    int c = ei[NE + e];
    atomicAdd(&cnt_all[r], 1);
    if (r != c) atomicAdd(&deg_keep[r], 1);
}

__global__ void dis_kernel(const int* __restrict__ deg, float* __restrict__ dis) {
    int n = blockIdx.x * 256 + threadIdx.x;
    if (n >= NN) return;
    int d = deg[n];
    dis[n] = (d > 0) ? rsqrtf((float)d) : 0.0f;
}

// inclusive scan of cnt within each 256-block; write per-block sums
__global__ void scan1_kernel(const int* __restrict__ cnt,
                             int* __restrict__ incl,
                             int* __restrict__ bsum) {
    __shared__ int s[256];
    int t = threadIdx.x;
    int idx = blockIdx.x * 256 + t;
    int v = (idx < NN) ? cnt[idx] : 0;
    s[t] = v;
    __syncthreads();
    for (int off = 1; off < 256; off <<= 1) {
        int add = (t >= off) ? s[t - off] : 0;
        __syncthreads();
        s[t] += add;
        __syncthreads();
    }
    if (idx < NN) incl[idx] = s[t];
    if (t == 255) bsum[blockIdx.x] = s[255];
}

// scan the block sums (nb <= 256); convert to exclusive offsets in-place
__global__ void scan2_kernel(int* __restrict__ bsum, int nb) {
    __shared__ int s[256];
    int t = threadIdx.x;
    int v = (t < nb) ? bsum[t] : 0;
    s[t] = v;
    __syncthreads();
    for (int off = 1; off < 256; off <<= 1) {
        int add = (t >= off) ? s[t - off] : 0;
        __syncthreads();
        s[t] += add;
        __syncthreads();
    }
    if (t < nb) bsum[t] = s[t] - v;   // exclusive
}

__global__ void scan3_kernel(const int* __restrict__ cnt,
                             const int* __restrict__ incl,
                             const int* __restrict__ bexcl,
                             int* __restrict__ row_ptr,
                             int* __restrict__ cursor) {
    int idx = blockIdx.x * 256 + threadIdx.x;
    if (idx == 0) row_ptr[NN] = NE;
    if (idx >= NN) return;
    int rp = incl[idx] - cnt[idx] + bexcl[blockIdx.x];
    row_ptr[idx] = rp;
    cursor[idx]  = rp;
}

__global__ void fill_kernel(const int* __restrict__ ei,
                            const float* __restrict__ ew,
                            const float* __restrict__ dis,
                            int* __restrict__ cursor,
                            int* __restrict__ csr_col,
                            float* __restrict__ csr_val) {
    int e = blockIdx.x * 256 + threadIdx.x;
    if (e >= NE) return;
    int r = ei[e];
    int c = ei[NE + e];
    int pos = atomicAdd(&cursor[r], 1);
    float w = (r != c) ? ew[e] : 0.0f;     // removed self-loops -> weight 0
    csr_col[pos] = c;
    csr_val[pos] = -dis[r] * w * dis[c];
}

// ---------------- SpMM: out[n][:] = alpha * sum_j val[j]*V[col[j]][:] - (use_sub ? sub[n][:] : 0)
// one wave (64 lanes) per node, lane t covers channels 4t..4t+3
__global__ __launch_bounds__(256)
void spmm_kernel(const float* __restrict__ V,
                 const float* __restrict__ sub,
                 const int* __restrict__ row_ptr,
                 const int* __restrict__ csr_col,
                 const float* __restrict__ csr_val,
                 float* __restrict__ out,
                 float alpha, int use_sub) {
    int wave = threadIdx.x >> 6;
    int lane = threadIdx.x & 63;
    int n = blockIdx.x * 4 + wave;          // grid is exactly NN/4 blocks
    int j0 = row_ptr[n];
    int j1 = row_ptr[n + 1];
    int cbase = lane * 4;
    float4 acc = make_float4(0.f, 0.f, 0.f, 0.f);
    for (int j = j0; j < j1; ++j) {
        int   col = csr_col[j];
        float w   = csr_val[j];
        float4 v = *(const float4*)&V[(long)col * C + cbase];
        acc.x += w * v.x; acc.y += w * v.y; acc.z += w * v.z; acc.w += w * v.w;
    }
    float4 res;
    if (use_sub) {
        float4 s = *(const float4*)&sub[(long)n * C + cbase];
        res.x = alpha * acc.x - s.x;
        res.y = alpha * acc.y - s.y;
        res.z = alpha * acc.z - s.z;
        res.w = alpha * acc.w - s.w;
    } else {
        res.x = alpha * acc.x; res.y = alpha * acc.y;
        res.z = alpha * acc.z; res.w = alpha * acc.w;
    }
    *(float4*)&out[(long)n * C + cbase] = res;
}

// ---------------- fp32 tiled GEMM: Cout[m][n] (+)= A[m][:256] @ B[:256][n]
// 128x128 tile per 256-thread block, 8x8 per-thread microtile, K-chunks of 16
__global__ __launch_bounds__(256)
void gemm_kernel(const float* __restrict__ A,
                 const float* __restrict__ B,
                 const float* __restrict__ bias,
                 float* __restrict__ Cout,
                 int addBias) {
    __shared__ float As[16][132];
    __shared__ float Bs[16][132];
    int tid = threadIdx.x;
    int m0 = blockIdx.x * 128;
    int n0 = blockIdx.y * 128;
    int tm = tid >> 4;
    int tn = tid & 15;

    float acc[8][8];
#pragma unroll
    for (int i = 0; i < 8; ++i)
#pragma unroll
        for (int j = 0; j < 8; ++j) acc[i][j] = 0.f;

    for (int k0 = 0; k0 < 256; k0 += 16) {
        // stage A (128 rows x 16 k), transposed into As[k][m]
#pragma unroll
        for (int i = 0; i < 2; ++i) {
            int idx4 = tid * 2 + i;          // 0..511
            int ml = idx4 >> 2;              // 0..127
            int kg = idx4 & 3;               // 0..3 (float4 group)
            int m = m0 + ml;
            float4 f = make_float4(0.f, 0.f, 0.f, 0.f);
            if (m < NN) f = *(const float4*)&A[(long)m * 256 + k0 + kg * 4];
            As[kg * 4 + 0][ml] = f.x;
            As[kg * 4 + 1][ml] = f.y;
            As[kg * 4 + 2][ml] = f.z;
            As[kg * 4 + 3][ml] = f.w;
        }
        // stage B (16 k x 128 n)
#pragma unroll
        for (int i = 0; i < 2; ++i) {
            int idx4 = tid * 2 + i;
            int kk = idx4 >> 5;              // 0..15
            int ng = idx4 & 31;              // 0..31
            float4 f = *(const float4*)&B[(long)(k0 + kk) * 256 + n0 + ng * 4];
            *(float4*)&Bs[kk][ng * 4] = f;
        }
        __syncthreads();
#pragma unroll
        for (int kk = 0; kk < 16; ++kk) {
            float a[8], b[8];
            *(float4*)&a[0] = *(const float4*)&As[kk][tm * 8];
            *(float4*)&a[4] = *(const float4*)&As[kk][tm * 8 + 4];
            *(float4*)&b[0] = *(const float4*)&Bs[kk][tn * 8];
            *(float4*)&b[4] = *(const float4*)&Bs[kk][tn * 8 + 4];
#pragma unroll
            for (int i = 0; i < 8; ++i)
#pragma unroll
                for (int j = 0; j < 8; ++j) acc[i][j] += a[i] * b[j];
        }
        __syncthreads();
    }

#pragma unroll
    for (int i = 0; i < 8; ++i) {
        int m = m0 + tm * 8 + i;
        if (m >= NN) continue;
#pragma unroll
        for (int j = 0; j < 8; j += 4) {
            int n = n0 + tn * 8 + j;
            float4 o;
            o.x = acc[i][j + 0]; o.y = acc[i][j + 1];
            o.z = acc[i][j + 2]; o.w = acc[i][j + 3];
            if (addBias) {
                float4 bb = *(const float4*)&bias[n];
                o.x += bb.x; o.y += bb.y; o.z += bb.z; o.w += bb.w;
            } else {
                float4 p = *(const float4*)&Cout[(long)m * 256 + n];
                o.x += p.x; o.y += p.y; o.z += p.z; o.w += p.w;
            }
            *(float4*)&Cout[(long)m * 256 + n] = o;
        }
    }
}

// ---------------- launch ----------------

extern "C" void kernel_launch(void* const* d_in, const int* in_sizes, int n_in,
                              void* d_out, int out_size, void* d_ws, size_t ws_size,
                              hipStream_t stream) {
    const float* x    = (const float*)d_in[0];
    const int*   ei   = (const int*)d_in[1];
    const float* ew   = (const float*)d_in[2];
    const float* W    = (const float*)d_in[3];   // [5][256][256]
    const float* bias = (const float*)d_in[4];
    float* out = (float*)d_out;

    // workspace carve (16B aligned chunks)
    char* p = (char*)d_ws;
    auto carve = [&](size_t bytes) {
        char* q = p;
        p += (bytes + 255) & ~(size_t)255;
        return q;
    };
    int*   deg     = (int*)  carve(NN * 4);
    int*   cnt     = (int*)  carve(NN * 4);
    int*   incl    = (int*)  carve(NN * 4);
    int*   bsum    = (int*)  carve(256 * 4);
    int*   row_ptr = (int*)  carve((NN + 1) * 4);
    int*   cursor  = (int*)  carve(NN * 4);
    int*   csr_col = (int*)  carve(NE * 4);
    float* csr_val = (float*)carve(NE * 4);
    float* dis     = (float*)carve(NN * 4);
    float* txA     = (float*)carve((size_t)NN * C * 4);
    float* txB     = (float*)carve((size_t)NN * C * 4);
    (void)ws_size; (void)n_in; (void)in_sizes; (void)out_size;

    const int NB_E = (NE + 255) / 256;   // 1250
    const int NB_N = (NN + 255) / 256;   // 157

    // zero deg + cnt (adjacent carves are not contiguous due to rounding; two memsets)
    hipMemsetAsync(deg, 0, NN * 4, stream);
    hipMemsetAsync(cnt, 0, NN * 4, stream);

    count_kernel<<<NB_E, 256, 0, stream>>>(ei, deg, cnt);
    dis_kernel<<<NB_N, 256, 0, stream>>>(deg, dis);
    scan1_kernel<<<NB_N, 256, 0, stream>>>(cnt, incl, bsum);
    scan2_kernel<<<1, 256, 0, stream>>>(bsum, NB_N);
    scan3_kernel<<<NB_N, 256, 0, stream>>>(cnt, incl, bsum, row_ptr, cursor);
    fill_kernel<<<NB_E, 256, 0, stream>>>(ei, ew, dis, cursor, csr_col, csr_val);

    dim3 ggrid(313, 2);

    // k = 0: out = x @ W0 + bias
    gemm_kernel<<<ggrid, 256, 0, stream>>>(x, W + 0 * 256 * 256, bias, out, 1);

    // tx1 = L x   (txB)
    spmm_kernel<<<NN / 4, 256, 0, stream>>>(x, nullptr, row_ptr, csr_col, csr_val,
                                            txB, 1.0f, 0);
    gemm_kernel<<<ggrid, 256, 0, stream>>>(txB, W + 1 * 256 * 256, bias, out, 0);

    // tx2 = 2 L tx1 - tx0   (txA; tx0 = x)
    spmm_kernel<<<NN / 4, 256, 0, stream>>>(txB, x, row_ptr, csr_col, csr_val,
                                            txA, 2.0f, 1);
    gemm_kernel<<<ggrid, 256, 0, stream>>>(txA, W + 2 * 256 * 256, bias, out, 0);

    // tx3 = 2 L tx2 - tx1   (in-place into txB)
    spmm_kernel<<<NN / 4, 256, 0, stream>>>(txA, txB, row_ptr, csr_col, csr_val,
                                            txB, 2.0f, 1);
    gemm_kernel<<<ggrid, 256, 0, stream>>>(txB, W + 3 * 256 * 256, bias, out, 0);

    // tx4 = 2 L tx3 - tx2   (in-place into txA)
    spmm_kernel<<<NN / 4, 256, 0, stream>>>(txB, txA, row_ptr, csr_col, csr_val,
                                            txA, 2.0f, 1);
    gemm_kernel<<<ggrid, 256, 0, stream>>>(txA, W + 4 * 256 * 256, bias, out, 0);
}

// Round 2
// 463.054 us; speedup vs baseline: 1.6377x; 1.6377x over previous
//
#include <hip/hip_runtime.h>

#define NN 40000
#define NE 320000
#define C 256
#define KORD 5
#define KT 1280          // fused K = 5 * 256
#define MPAD 40064       // 313 * 128 (GEMM row padding for safe over-read)

typedef __attribute__((ext_vector_type(8))) short short8;   // 8 x bf16 (4 VGPR)
typedef __attribute__((ext_vector_type(4))) float floatx4;  // 4 x f32
typedef unsigned short bf16_t;

__device__ __forceinline__ bf16_t f2bf(float f) {
    union { float f; unsigned u; } v; v.f = f;
    unsigned r = v.u + 0x7fffu + ((v.u >> 16) & 1u);  // RTNE
    return (bf16_t)(r >> 16);
}

#define GLL16(gsrc, ldst)                                                        \
    __builtin_amdgcn_global_load_lds(                                            \
        (const __attribute__((address_space(1))) void*)(gsrc),                   \
        (__attribute__((address_space(3))) void*)(ldst), 16, 0, 0)

// ---------------- graph preprocessing ----------------

__global__ void count_kernel(const int* __restrict__ ei,
                             int* __restrict__ deg_keep,
                             int* __restrict__ cnt_all) {
    int e = blockIdx.x * 256 + threadIdx.x;
    if (e >= NE) return;
    int r = ei[e];
    int c = ei[NE + e];
    atomicAdd(&cnt_all[r], 1);
    if (r != c) atomicAdd(&deg_keep[r], 1);
}

__global__ void dis_kernel(const int* __restrict__ deg, float* __restrict__ dis) {
    int n = blockIdx.x * 256 + threadIdx.x;
    if (n >= NN) return;
    int d = deg[n];
    dis[n] = (d > 0) ? rsqrtf((float)d) : 0.0f;
}

__global__ void scan1_kernel(const int* __restrict__ cnt,
                             int* __restrict__ incl,
                             int* __restrict__ bsum) {
    __shared__ int s[256];
    int t = threadIdx.x;
    int idx = blockIdx.x * 256 + t;
    int v = (idx < NN) ? cnt[idx] : 0;
    s[t] = v;
    __syncthreads();
    for (int off = 1; off < 256; off <<= 1) {
        int add = (t >= off) ? s[t - off] : 0;
        __syncthreads();
        s[t] += add;
        __syncthreads();
    }
    if (idx < NN) incl[idx] = s[t];
    if (t == 255) bsum[blockIdx.x] = s[255];
}

__global__ void scan2_kernel(int* __restrict__ bsum, int nb) {
    __shared__ int s[256];
    int t = threadIdx.x;
    int v = (t < nb) ? bsum[t] : 0;
    s[t] = v;
    __syncthreads();
    for (int off = 1; off < 256; off <<= 1) {
        int add = (t >= off) ? s[t - off] : 0;
        __syncthreads();
        s[t] += add;
        __syncthreads();
    }
    if (t < nb) bsum[t] = s[t] - v;   // exclusive
}

__global__ void scan3_kernel(const int* __restrict__ cnt,
                             const int* __restrict__ incl,
                             const int* __restrict__ bexcl,
                             int* __restrict__ row_ptr,
                             int* __restrict__ cursor) {
    int idx = blockIdx.x * 256 + threadIdx.x;
    if (idx == 0) row_ptr[NN] = NE;
    if (idx >= NN) return;
    int rp = incl[idx] - cnt[idx] + bexcl[blockIdx.x];
    row_ptr[idx] = rp;
    cursor[idx]  = rp;
}

__global__ void fill_kernel(const int* __restrict__ ei,
                            const float* __restrict__ ew,
                            const float* __restrict__ dis,
                            int* __restrict__ cursor,
                            int* __restrict__ csr_col,
                            float* __restrict__ csr_val) {
    int e = blockIdx.x * 256 + threadIdx.x;
    if (e >= NE) return;
    int r = ei[e];
    int c = ei[NE + e];
    int pos = atomicAdd(&cursor[r], 1);
    float w = (r != c) ? ew[e] : 0.0f;     // removed self-loops -> weight 0
    csr_col[pos] = c;
    csr_val[pos] = -dis[r] * w * dis[c];
}

// convert x (fp32 [NN][256]) into bf16 A-chunk 0 of [MPAD][KT]
__global__ void convx_kernel(const float* __restrict__ x, bf16_t* __restrict__ abf) {
    int i = blockIdx.x * 256 + threadIdx.x;
    if (i >= NN * 64) return;
    int n = i >> 6, cg = i & 63;
    float4 f = *(const float4*)&x[(size_t)n * C + cg * 4];
    ushort4 h;
    h.x = f2bf(f.x); h.y = f2bf(f.y); h.z = f2bf(f.z); h.w = f2bf(f.w);
    *(ushort4*)&abf[(size_t)n * KT + cg * 4] = h;
}

// transpose+convert W[5][256][256] -> WT[n(256)][kt(1280)] bf16
__global__ void wt_kernel(const float* __restrict__ W, bf16_t* __restrict__ WT) {
    int t = blockIdx.x * 256 + threadIdx.x;
    if (t >= 256 * KT) return;
    int n = t & 255, kt = t >> 8;
    WT[(size_t)n * KT + kt] = f2bf(W[(size_t)kt * 256 + n]);
}

// ---------------- SpMM ----------------
// out[n][:] = alpha * sum_j val[j]*V[col[j]][:] - (use_sub ? sub[n][:] : 0)
// Also writes bf16 copy into fused-A chunk (abf column block).
__global__ __launch_bounds__(256)
void spmm_kernel(const float* __restrict__ V,
                 const float* __restrict__ sub,
                 const int* __restrict__ row_ptr,
                 const int* __restrict__ csr_col,
                 const float* __restrict__ csr_val,
                 float* __restrict__ out,
                 bf16_t* __restrict__ abf,   // base of [MPAD][KT] + cheb*256 column offset
                 float alpha, int use_sub) {
    int wave = threadIdx.x >> 6;
    int lane = threadIdx.x & 63;
    int n = blockIdx.x * 4 + wave;          // grid is exactly NN/4 blocks
    int j0 = row_ptr[n];
    int j1 = row_ptr[n + 1];
    int cbase = lane * 4;
    float4 acc = make_float4(0.f, 0.f, 0.f, 0.f);
    for (int j = j0; j < j1; ++j) {
        int   col = csr_col[j];
        float w   = csr_val[j];
        float4 v = *(const float4*)&V[(size_t)col * C + cbase];
        acc.x += w * v.x; acc.y += w * v.y; acc.z += w * v.z; acc.w += w * v.w;
    }
    float4 res;
    if (use_sub) {
        float4 s = *(const float4*)&sub[(size_t)n * C + cbase];
        res.x = alpha * acc.x - s.x;
        res.y = alpha * acc.y - s.y;
        res.z = alpha * acc.z - s.z;
        res.w = alpha * acc.w - s.w;
    } else {
        res.x = alpha * acc.x; res.y = alpha * acc.y;
        res.z = alpha * acc.z; res.w = alpha * acc.w;
    }
    *(float4*)&out[(size_t)n * C + cbase] = res;
    ushort4 h;
    h.x = f2bf(res.x); h.y = f2bf(res.y); h.z = f2bf(res.z); h.w = f2bf(res.w);
    *(ushort4*)&abf[(size_t)n * KT + cbase] = h;
}

// ---------------- fused bf16 MFMA GEMM ----------------
// out[M=40000][256] = Abf[M][1280] @ WT^T (WT is [256][1280]) + bias
// 128x128 tile / block, 4 waves, each wave 64x64 via 4x4 mfma_f32_16x16x32_bf16.
// LDS: As 8KB + Bs 8KB, both [row][4 granules of 16B], granule XOR-swizzled
// (g ^ ((row>>1)&3)) so wave64 ds_read_b128 is uniformly 2-way (free).
__global__ __launch_bounds__(256, 2)
void gemm_mfma(const bf16_t* __restrict__ Abf,  // [MPAD][KT]
               const bf16_t* __restrict__ WT,   // [256][KT]
               const float* __restrict__ bias,
               float* __restrict__ out) {
    __shared__ bf16_t smem[8192];   // 16 KB: As = [0,4096), Bs = [4096,8192) elements
    int tid = threadIdx.x;
    int w = tid >> 6, lane = tid & 63;
    int m0 = blockIdx.x * 128;
    int n0 = blockIdx.y * 128;
    int wm = w & 1, wn = w >> 1;
    int quad = lane >> 4, l16 = lane & 15;

    // staging source addresses: LDS granule gi = (w*4+j)*64 + lane, fixed per lane.
    const bf16_t* srcbase[4];
    for (int j = 0; j < 4; ++j) {
        int gi = (w * 4 + j) * 64 + lane;           // 0..1023
        int t  = (gi >= 512) ? gi - 512 : gi;       // granule within tile
        int m  = t >> 2;                            // tile row (A: m_local, B: n_local)
        int pg = t & 3;
        int g  = pg ^ ((m >> 1) & 3);               // logical k-granule for this slot
        srcbase[j] = (gi >= 512 ? WT + (size_t)(n0 + m) * KT
                                : Abf + (size_t)(m0 + m) * KT) + g * 8;
    }

    // fragment read offsets (element units; +mt*512 / +nt*512 for the 16-row steps,
    // swizzle term invariant under +16 rows)
    int arow = wm * 64 + l16;
    int brow = wn * 64 + l16;
    int aoff0 = (arow * 4 + (quad ^ ((arow >> 1) & 3))) * 8;
    int boff0 = 4096 + (brow * 4 + (quad ^ ((brow >> 1) & 3))) * 8;

    floatx4 acc[4][4] = {};

    for (int k0 = 0; k0 < KT; k0 += 32) {
        __syncthreads();   // previous iter's LDS reads done before overwrite
#pragma unroll
        for (int j = 0; j < 4; ++j)
            GLL16(srcbase[j] + k0, &smem[(w * 4 + j) * 512]);
        __syncthreads();

        short8 af[4], bfr[4];
#pragma unroll
        for (int mt = 0; mt < 4; ++mt) af[mt]  = *(const short8*)&smem[aoff0 + mt * 512];
#pragma unroll
        for (int nt = 0; nt < 4; ++nt) bfr[nt] = *(const short8*)&smem[boff0 + nt * 512];
#pragma unroll
        for (int mt = 0; mt < 4; ++mt)
#pragma unroll
            for (int nt = 0; nt < 4; ++nt)
                acc[mt][nt] = __builtin_amdgcn_mfma_f32_16x16x32_bf16(
                    af[mt], bfr[nt], acc[mt][nt], 0, 0, 0);
    }

    // epilogue: C/D layout col=lane&15, row=quad*4+reg  (m89-verified)
#pragma unroll
    for (int nt = 0; nt < 4; ++nt) {
        int n = n0 + wn * 64 + nt * 16 + l16;
        float bv = bias[n];
#pragma unroll
        for (int mt = 0; mt < 4; ++mt) {
            int mbase = m0 + wm * 64 + mt * 16 + quad * 4;
#pragma unroll
            for (int r = 0; r < 4; ++r) {
                int m = mbase + r;
                if (m < NN) out[(size_t)m * C + n] = acc[mt][nt][r] + bv;
            }
        }
    }
}

// ---------------- launch ----------------

extern "C" void kernel_launch(void* const* d_in, const int* in_sizes, int n_in,
                              void* d_out, int out_size, void* d_ws, size_t ws_size,
                              hipStream_t stream) {
    const float* x    = (const float*)d_in[0];
    const int*   ei   = (const int*)d_in[1];
    const float* ew   = (const float*)d_in[2];
    const float* W    = (const float*)d_in[3];   // [5][256][256]
    const float* bias = (const float*)d_in[4];
    float* out = (float*)d_out;

    char* p = (char*)d_ws;
    auto carve = [&](size_t bytes) {
        char* q = p;
        p += (bytes + 255) & ~(size_t)255;
        return q;
    };
    int*    deg     = (int*)   carve(NN * 4);
    int*    cnt     = (int*)   carve(NN * 4);
    int*    incl    = (int*)   carve(NN * 4);
    int*    bsum    = (int*)   carve(256 * 4);
    int*    row_ptr = (int*)   carve((NN + 1) * 4);
    int*    cursor  = (int*)   carve(NN * 4);
    int*    csr_col = (int*)   carve(NE * 4);
    float*  csr_val = (float*) carve(NE * 4);
    float*  dis     = (float*) carve(NN * 4);
    float*  txA     = (float*) carve((size_t)NN * C * 4);
    float*  txB     = (float*) carve((size_t)NN * C * 4);
    bf16_t* abf     = (bf16_t*)carve((size_t)MPAD * KT * 2);   // fused bf16 A
    bf16_t* WT      = (bf16_t*)carve((size_t)C * KT * 2);      // W transposed bf16
    (void)ws_size; (void)n_in; (void)in_sizes; (void)out_size;

    const int NB_E = (NE + 255) / 256;   // 1250
    const int NB_N = (NN + 255) / 256;   // 157

    hipMemsetAsync(deg, 0, NN * 4, stream);
    hipMemsetAsync(cnt, 0, NN * 4, stream);

    count_kernel<<<NB_E, 256, 0, stream>>>(ei, deg, cnt);
    dis_kernel<<<NB_N, 256, 0, stream>>>(deg, dis);
    scan1_kernel<<<NB_N, 256, 0, stream>>>(cnt, incl, bsum);
    scan2_kernel<<<1, 256, 0, stream>>>(bsum, NB_N);
    scan3_kernel<<<NB_N, 256, 0, stream>>>(cnt, incl, bsum, row_ptr, cursor);
    fill_kernel<<<NB_E, 256, 0, stream>>>(ei, ew, dis, cursor, csr_col, csr_val);

    convx_kernel<<<(NN * 64 + 255) / 256, 256, 0, stream>>>(x, abf);
    wt_kernel<<<(256 * KT + 255) / 256, 256, 0, stream>>>(W, WT);

    // Chebyshev recursion (fp32), each SpMM also emits bf16 into abf chunk k
    // tx1 = L x
    spmm_kernel<<<NN / 4, 256, 0, stream>>>(x, nullptr, row_ptr, csr_col, csr_val,
                                            txB, abf + 1 * 256, 1.0f, 0);
    // tx2 = 2 L tx1 - x
    spmm_kernel<<<NN / 4, 256, 0, stream>>>(txB, x, row_ptr, csr_col, csr_val,
                                            txA, abf + 2 * 256, 2.0f, 1);
    // tx3 = 2 L tx2 - tx1   (in-place into txB)
    spmm_kernel<<<NN / 4, 256, 0, stream>>>(txA, txB, row_ptr, csr_col, csr_val,
                                            txB, abf + 3 * 256, 2.0f, 1);
    // tx4 = 2 L tx3 - tx2   (in-place into txA)
    spmm_kernel<<<NN / 4, 256, 0, stream>>>(txB, txA, row_ptr, csr_col, csr_val,
                                            txA, abf + 4 * 256, 2.0f, 1);

    // fused GEMM: out = abf @ WT^T + bias
    dim3 ggrid(313, 2);
    gemm_mfma<<<ggrid, 256, 0, stream>>>(abf, WT, bias, out);
}

// Round 3
// 447.120 us; speedup vs baseline: 1.6961x; 1.0356x over previous
//
#include <hip/hip_runtime.h>

#define NN 40000
#define NE 320000
#define C 256
#define KORD 5
#define KT 1280          // fused K = 5 * 256
#define MPAD 40064       // 313 * 128 (GEMM row padding for safe over-read)

typedef __attribute__((ext_vector_type(8))) short short8;   // 8 x bf16 (4 VGPR)
typedef __attribute__((ext_vector_type(4))) float floatx4;  // 4 x f32
typedef unsigned short bf16_t;

__device__ __forceinline__ bf16_t f2bf(float f) {
    union { float f; unsigned u; } v; v.f = f;
    unsigned r = v.u + 0x7fffu + ((v.u >> 16) & 1u);  // RTNE
    return (bf16_t)(r >> 16);
}
__device__ __forceinline__ float bf2f(bf16_t h) {
    union { unsigned u; float f; } v; v.u = ((unsigned)h) << 16;
    return v.f;
}

#define GLL16(gsrc, ldst)                                                        \
    __builtin_amdgcn_global_load_lds(                                            \
        (const __attribute__((address_space(1))) void*)(gsrc),                   \
        (__attribute__((address_space(3))) void*)(ldst), 16, 0, 0)

// ---------------- graph preprocessing ----------------

__global__ void count_kernel(const int* __restrict__ ei,
                             int* __restrict__ deg_keep,
                             int* __restrict__ cnt_all) {
    int e = blockIdx.x * 256 + threadIdx.x;
    if (e >= NE) return;
    int r = ei[e];
    int c = ei[NE + e];
    atomicAdd(&cnt_all[r], 1);
    if (r != c) atomicAdd(&deg_keep[r], 1);
}

__global__ void dis_kernel(const int* __restrict__ deg, float* __restrict__ dis) {
    int n = blockIdx.x * 256 + threadIdx.x;
    if (n >= NN) return;
    int d = deg[n];
    dis[n] = (d > 0) ? rsqrtf((float)d) : 0.0f;
}

__global__ void scan1_kernel(const int* __restrict__ cnt,
                             int* __restrict__ incl,
                             int* __restrict__ bsum) {
    __shared__ int s[256];
    int t = threadIdx.x;
    int idx = blockIdx.x * 256 + t;
    int v = (idx < NN) ? cnt[idx] : 0;
    s[t] = v;
    __syncthreads();
    for (int off = 1; off < 256; off <<= 1) {
        int add = (t >= off) ? s[t - off] : 0;
        __syncthreads();
        s[t] += add;
        __syncthreads();
    }
    if (idx < NN) incl[idx] = s[t];
    if (t == 255) bsum[blockIdx.x] = s[255];
}

__global__ void scan2_kernel(int* __restrict__ bsum, int nb) {
    __shared__ int s[256];
    int t = threadIdx.x;
    int v = (t < nb) ? bsum[t] : 0;
    s[t] = v;
    __syncthreads();
    for (int off = 1; off < 256; off <<= 1) {
        int add = (t >= off) ? s[t - off] : 0;
        __syncthreads();
        s[t] += add;
        __syncthreads();
    }
    if (t < nb) bsum[t] = s[t] - v;   // exclusive
}

__global__ void scan3_kernel(const int* __restrict__ cnt,
                             const int* __restrict__ incl,
                             const int* __restrict__ bexcl,
                             int* __restrict__ row_ptr,
                             int* __restrict__ cursor) {
    int idx = blockIdx.x * 256 + threadIdx.x;
    if (idx == 0) row_ptr[NN] = NE;
    if (idx >= NN) return;
    int rp = incl[idx] - cnt[idx] + bexcl[blockIdx.x];
    row_ptr[idx] = rp;
    cursor[idx]  = rp;
}

__global__ void fill_kernel(const int* __restrict__ ei,
                            const float* __restrict__ ew,
                            const float* __restrict__ dis,
                            int* __restrict__ cursor,
                            int* __restrict__ csr_col,
                            float* __restrict__ csr_val) {
    int e = blockIdx.x * 256 + threadIdx.x;
    if (e >= NE) return;
    int r = ei[e];
    int c = ei[NE + e];
    int pos = atomicAdd(&cursor[r], 1);
    float w = (r != c) ? ew[e] : 0.0f;     // removed self-loops -> weight 0
    csr_col[pos] = c;
    csr_val[pos] = -dis[r] * w * dis[c];
}

// convert x (fp32 [NN][256]) into bf16 A-chunk 0 of [MPAD][KT]
__global__ void convx_kernel(const float* __restrict__ x, bf16_t* __restrict__ abf) {
    int i = blockIdx.x * 256 + threadIdx.x;
    if (i >= NN * 64) return;
    int n = i >> 6, cg = i & 63;
    float4 f = *(const float4*)&x[(size_t)n * C + cg * 4];
    ushort4 h;
    h.x = f2bf(f.x); h.y = f2bf(f.y); h.z = f2bf(f.z); h.w = f2bf(f.w);
    *(ushort4*)&abf[(size_t)n * KT + cg * 4] = h;
}

// transpose+convert W[5][256][256] -> WT[n(256)][kt(1280)] bf16
__global__ void wt_kernel(const float* __restrict__ W, bf16_t* __restrict__ WT) {
    int t = blockIdx.x * 256 + threadIdx.x;
    if (t >= 256 * KT) return;
    int n = t & 255, kt = t >> 8;
    WT[(size_t)n * KT + kt] = f2bf(W[(size_t)kt * 256 + n]);
}

// ---------------- SpMM (bf16 state) ----------------
// outb[n][:] = bf16( alpha * sum_j val[j]*Vb[col[j]][:] - (use_sub ? subb[n][:] : 0) )
// All chunks live inside the fused-A buffer [*][KT]; gather/sub/write chunks
// never alias (k-1 / k-2 / k). One wave per node, lane t covers channels 4t..4t+3.
__global__ __launch_bounds__(256)
void spmm_kernel(const bf16_t* __restrict__ Vb,
                 const bf16_t* __restrict__ subb,
                 const int* __restrict__ row_ptr,
                 const int* __restrict__ csr_col,
                 const float* __restrict__ csr_val,
                 bf16_t* __restrict__ outb,
                 float alpha, int use_sub) {
    int wave = threadIdx.x >> 6;
    int lane = threadIdx.x & 63;
    int n = blockIdx.x * 4 + wave;          // grid is exactly NN/4 blocks
    int j0 = row_ptr[n];
    int j1 = row_ptr[n + 1];
    int cb = lane * 4;
    float a0 = 0.f, a1 = 0.f, a2 = 0.f, a3 = 0.f;
    for (int j = j0; j < j1; ++j) {
        int   col = csr_col[j];
        float w   = csr_val[j];
        ushort4 v = *(const ushort4*)&Vb[(size_t)col * KT + cb];
        a0 += w * bf2f(v.x); a1 += w * bf2f(v.y);
        a2 += w * bf2f(v.z); a3 += w * bf2f(v.w);
    }
    float r0, r1, r2, r3;
    if (use_sub) {
        ushort4 s = *(const ushort4*)&subb[(size_t)n * KT + cb];
        r0 = alpha * a0 - bf2f(s.x);
        r1 = alpha * a1 - bf2f(s.y);
        r2 = alpha * a2 - bf2f(s.z);
        r3 = alpha * a3 - bf2f(s.w);
    } else {
        r0 = alpha * a0; r1 = alpha * a1; r2 = alpha * a2; r3 = alpha * a3;
    }
    ushort4 h;
    h.x = f2bf(r0); h.y = f2bf(r1); h.z = f2bf(r2); h.w = f2bf(r3);
    *(ushort4*)&outb[(size_t)n * KT + cb] = h;
}

// ---------------- fused bf16 MFMA GEMM, split-K=2 ----------------
// out[M=40000][256] += Abf[M][kz-half of 1280] @ WT^T + (kz==0 ? bias : 0)
// out must be pre-zeroed. 128x128 tile / block, 4 waves, 4x4 mfma_16x16x32_bf16.
// LDS granule XOR-swizzle -> wave64 ds_read_b128 is uniformly 2-way (free).
__global__ __launch_bounds__(256, 2)
void gemm_mfma(const bf16_t* __restrict__ Abf,  // [MPAD][KT]
               const bf16_t* __restrict__ WT,   // [256][KT]
               const float* __restrict__ bias,
               float* __restrict__ out) {
    __shared__ bf16_t smem[8192];   // 16 KB: As = [0,4096), Bs = [4096,8192) elements
    int tid = threadIdx.x;
    int w = tid >> 6, lane = tid & 63;
    int m0 = blockIdx.x * 128;
    int n0 = blockIdx.y * 128;
    int kz = blockIdx.z;
    int wm = w & 1, wn = w >> 1;
    int quad = lane >> 4, l16 = lane & 15;

    // staging source addresses: LDS granule gi = (w*4+j)*64 + lane, fixed per lane.
    const bf16_t* srcbase[4];
    for (int j = 0; j < 4; ++j) {
        int gi = (w * 4 + j) * 64 + lane;           // 0..1023
        int t  = (gi >= 512) ? gi - 512 : gi;       // granule within tile
        int m  = t >> 2;                            // tile row (A: m_local, B: n_local)
        int pg = t & 3;
        int g  = pg ^ ((m >> 1) & 3);               // logical k-granule for this slot
        srcbase[j] = (gi >= 512 ? WT + (size_t)(n0 + m) * KT
                                : Abf + (size_t)(m0 + m) * KT) + g * 8;
    }

    int arow = wm * 64 + l16;
    int brow = wn * 64 + l16;
    int aoff0 = (arow * 4 + (quad ^ ((arow >> 1) & 3))) * 8;
    int boff0 = 4096 + (brow * 4 + (quad ^ ((brow >> 1) & 3))) * 8;

    floatx4 acc[4][4] = {};

    const int kbeg = kz * (KT / 2), kend = kbeg + KT / 2;
    for (int k0 = kbeg; k0 < kend; k0 += 32) {
        __syncthreads();   // previous iter's LDS reads done before overwrite
#pragma unroll
        for (int j = 0; j < 4; ++j)
            GLL16(srcbase[j] + k0, &smem[(w * 4 + j) * 512]);
        __syncthreads();

        short8 af[4], bfr[4];
#pragma unroll
        for (int mt = 0; mt < 4; ++mt) af[mt]  = *(const short8*)&smem[aoff0 + mt * 512];
#pragma unroll
        for (int nt = 0; nt < 4; ++nt) bfr[nt] = *(const short8*)&smem[boff0 + nt * 512];
#pragma unroll
        for (int mt = 0; mt < 4; ++mt)
#pragma unroll
            for (int nt = 0; nt < 4; ++nt)
                acc[mt][nt] = __builtin_amdgcn_mfma_f32_16x16x32_bf16(
                    af[mt], bfr[nt], acc[mt][nt], 0, 0, 0);
    }

    // epilogue: C/D layout col=lane&15, row=quad*4+reg  (m89-verified)
#pragma unroll
    for (int nt = 0; nt < 4; ++nt) {
        int n = n0 + wn * 64 + nt * 16 + l16;
        float bv = (kz == 0) ? bias[n] : 0.f;
#pragma unroll
        for (int mt = 0; mt < 4; ++mt) {
            int mbase = m0 + wm * 64 + mt * 16 + quad * 4;
#pragma unroll
            for (int r = 0; r < 4; ++r) {
                int m = mbase + r;
                if (m < NN) atomicAdd(&out[(size_t)m * C + n], acc[mt][nt][r] + bv);
            }
        }
    }
}

// ---------------- launch ----------------

extern "C" void kernel_launch(void* const* d_in, const int* in_sizes, int n_in,
                              void* d_out, int out_size, void* d_ws, size_t ws_size,
                              hipStream_t stream) {
    const float* x    = (const float*)d_in[0];
    const int*   ei   = (const int*)d_in[1];
    const float* ew   = (const float*)d_in[2];
    const float* W    = (const float*)d_in[3];   // [5][256][256]
    const float* bias = (const float*)d_in[4];
    float* out = (float*)d_out;

    char* p = (char*)d_ws;
    auto carve = [&](size_t bytes) {
        char* q = p;
        p += (bytes + 255) & ~(size_t)255;
        return q;
    };
    int*    deg     = (int*)   carve(NN * 4);
    int*    cnt     = (int*)   carve(NN * 4);
    int*    incl    = (int*)   carve(NN * 4);
    int*    bsum    = (int*)   carve(256 * 4);
    int*    row_ptr = (int*)   carve((NN + 1) * 4);
    int*    cursor  = (int*)   carve(NN * 4);
    int*    csr_col = (int*)   carve(NE * 4);
    float*  csr_val = (float*) carve(NE * 4);
    float*  dis     = (float*) carve(NN * 4);
    bf16_t* abf     = (bf16_t*)carve((size_t)MPAD * KT * 2);   // fused bf16 A (recursion state)
    bf16_t* WT      = (bf16_t*)carve((size_t)C * KT * 2);      // W transposed bf16
    (void)ws_size; (void)n_in; (void)in_sizes; (void)out_size;

    const int NB_E = (NE + 255) / 256;   // 1250
    const int NB_N = (NN + 255) / 256;   // 157

    hipMemsetAsync(deg, 0, NN * 4, stream);
    hipMemsetAsync(cnt, 0, NN * 4, stream);
    hipMemsetAsync(out, 0, (size_t)NN * C * 4, stream);   // split-K accumulates atomically

    count_kernel<<<NB_E, 256, 0, stream>>>(ei, deg, cnt);
    dis_kernel<<<NB_N, 256, 0, stream>>>(deg, dis);
    scan1_kernel<<<NB_N, 256, 0, stream>>>(cnt, incl, bsum);
    scan2_kernel<<<1, 256, 0, stream>>>(bsum, NB_N);
    scan3_kernel<<<NB_N, 256, 0, stream>>>(cnt, incl, bsum, row_ptr, cursor);
    fill_kernel<<<NB_E, 256, 0, stream>>>(ei, ew, dis, cursor, csr_col, csr_val);

    convx_kernel<<<(NN * 64 + 255) / 256, 256, 0, stream>>>(x, abf);
    wt_kernel<<<(256 * KT + 255) / 256, 256, 0, stream>>>(W, WT);

    // Chebyshev recursion, bf16 state in abf chunks 0..4 (chunk k at abf + k*256)
    // tx1 = L x
    spmm_kernel<<<NN / 4, 256, 0, stream>>>(abf + 0 * 256, nullptr, row_ptr, csr_col,
                                            csr_val, abf + 1 * 256, 1.0f, 0);
    // tx2 = 2 L tx1 - tx0
    spmm_kernel<<<NN / 4, 256, 0, stream>>>(abf + 1 * 256, abf + 0 * 256, row_ptr,
                                            csr_col, csr_val, abf + 2 * 256, 2.0f, 1);
    // tx3 = 2 L tx2 - tx1
    spmm_kernel<<<NN / 4, 256, 0, stream>>>(abf + 2 * 256, abf + 1 * 256, row_ptr,
                                            csr_col, csr_val, abf + 3 * 256, 2.0f, 1);
    // tx4 = 2 L tx3 - tx2
    spmm_kernel<<<NN / 4, 256, 0, stream>>>(abf + 3 * 256, abf + 2 * 256, row_ptr,
                                            csr_col, csr_val, abf + 4 * 256, 2.0f, 1);

    // fused GEMM: out = abf @ WT^T + bias, split-K=2
    dim3 ggrid(313, 2, 2);
    gemm_mfma<<<ggrid, 256, 0, stream>>>(abf, WT, bias, out);
}

// Round 4
// 325.706 us; speedup vs baseline: 2.3283x; 1.3728x over previous
//
#include <hip/hip_runtime.h>

#define NN 40000
#define NE 320000
#define C 256
#define KORD 5
#define KT 1280          // fused K = 5 * 256
#define MPAD 40064       // 313 * 128 (GEMM row padding for safe over-read)

typedef __attribute__((ext_vector_type(8))) short short8;   // 8 x bf16 (4 VGPR)
typedef __attribute__((ext_vector_type(4))) float floatx4;  // 4 x f32
typedef unsigned short bf16_t;

__device__ __forceinline__ bf16_t f2bf(float f) {
    union { float f; unsigned u; } v; v.f = f;
    unsigned r = v.u + 0x7fffu + ((v.u >> 16) & 1u);  // RTNE
    return (bf16_t)(r >> 16);
}
__device__ __forceinline__ float bf2f(bf16_t h) {
    union { unsigned u; float f; } v; v.u = ((unsigned)h) << 16;
    return v.f;
}

#define GLL16(gsrc, ldst)                                                        \
    __builtin_amdgcn_global_load_lds(                                            \
        (const __attribute__((address_space(1))) void*)(gsrc),                   \
        (__attribute__((address_space(3))) void*)(ldst), 16, 0, 0)

// ---------------- graph preprocessing ----------------

__global__ void count_kernel(const int* __restrict__ ei,
                             int* __restrict__ deg_keep,
                             int* __restrict__ cnt_all) {
    int e = blockIdx.x * 256 + threadIdx.x;
    if (e >= NE) return;
    int r = ei[e];
    int c = ei[NE + e];
    atomicAdd(&cnt_all[r], 1);
    if (r != c) atomicAdd(&deg_keep[r], 1);
}

__global__ void dis_kernel(const int* __restrict__ deg, float* __restrict__ dis) {
    int n = blockIdx.x * 256 + threadIdx.x;
    if (n >= NN) return;
    int d = deg[n];
    dis[n] = (d > 0) ? rsqrtf((float)d) : 0.0f;
}

__global__ void scan1_kernel(const int* __restrict__ cnt,
                             int* __restrict__ incl,
                             int* __restrict__ bsum) {
    __shared__ int s[256];
    int t = threadIdx.x;
    int idx = blockIdx.x * 256 + t;
    int v = (idx < NN) ? cnt[idx] : 0;
    s[t] = v;
    __syncthreads();
    for (int off = 1; off < 256; off <<= 1) {
        int add = (t >= off) ? s[t - off] : 0;
        __syncthreads();
        s[t] += add;
        __syncthreads();
    }
    if (idx < NN) incl[idx] = s[t];
    if (t == 255) bsum[blockIdx.x] = s[255];
}

__global__ void scan2_kernel(int* __restrict__ bsum, int nb) {
    __shared__ int s[256];
    int t = threadIdx.x;
    int v = (t < nb) ? bsum[t] : 0;
    s[t] = v;
    __syncthreads();
    for (int off = 1; off < 256; off <<= 1) {
        int add = (t >= off) ? s[t - off] : 0;
        __syncthreads();
        s[t] += add;
        __syncthreads();
    }
    if (t < nb) bsum[t] = s[t] - v;   // exclusive
}

__global__ void scan3_kernel(const int* __restrict__ cnt,
                             const int* __restrict__ incl,
                             const int* __restrict__ bexcl,
                             int* __restrict__ row_ptr,
                             int* __restrict__ cursor) {
    int idx = blockIdx.x * 256 + threadIdx.x;
    if (idx == 0) row_ptr[NN] = NE;
    if (idx >= NN) return;
    int rp = incl[idx] - cnt[idx] + bexcl[blockIdx.x];
    row_ptr[idx] = rp;
    cursor[idx]  = rp;
}

__global__ void fill_kernel(const int* __restrict__ ei,
                            const float* __restrict__ ew,
                            const float* __restrict__ dis,
                            int* __restrict__ cursor,
                            int* __restrict__ csr_col,
                            float* __restrict__ csr_val) {
    int e = blockIdx.x * 256 + threadIdx.x;
    if (e >= NE) return;
    int r = ei[e];
    int c = ei[NE + e];
    int pos = atomicAdd(&cursor[r], 1);
    float w = (r != c) ? ew[e] : 0.0f;     // removed self-loops -> weight 0
    csr_col[pos] = c;
    csr_val[pos] = -dis[r] * w * dis[c];
}

// convert x (fp32 [NN][256]) into bf16 A-chunk 0 of [MPAD][KT]
__global__ void convx_kernel(const float* __restrict__ x, bf16_t* __restrict__ abf) {
    int i = blockIdx.x * 256 + threadIdx.x;
    if (i >= NN * 64) return;
    int n = i >> 6, cg = i & 63;
    float4 f = *(const float4*)&x[(size_t)n * C + cg * 4];
    ushort4 h;
    h.x = f2bf(f.x); h.y = f2bf(f.y); h.z = f2bf(f.z); h.w = f2bf(f.w);
    *(ushort4*)&abf[(size_t)n * KT + cg * 4] = h;
}

// transpose+convert W[5][256][256] -> WT[n(256)][kt(1280)] bf16
__global__ void wt_kernel(const float* __restrict__ W, bf16_t* __restrict__ WT) {
    int t = blockIdx.x * 256 + threadIdx.x;
    if (t >= 256 * KT) return;
    int n = t & 255, kt = t >> 8;
    WT[(size_t)n * KT + kt] = f2bf(W[(size_t)kt * 256 + n]);
}

// ---------------- SpMM (bf16 state, MLP-optimized) ----------------
// outb[n][:] = bf16( alpha * sum_j val[j]*Vb[col[j]][:] - (use_sub ? subb[n][:] : 0) )
// One wave per node (wave id via readfirstlane -> scalar index loads);
// unroll-by-4 gather for 4 outstanding vector loads per wave.
__global__ __launch_bounds__(256)
void spmm_kernel(const bf16_t* __restrict__ Vb,
                 const bf16_t* __restrict__ subb,
                 const int* __restrict__ row_ptr,
                 const int* __restrict__ csr_col,
                 const float* __restrict__ csr_val,
                 bf16_t* __restrict__ outb,
                 float alpha, int use_sub) {
    int wave = __builtin_amdgcn_readfirstlane(threadIdx.x >> 6);  // wave-uniform
    int lane = threadIdx.x & 63;
    int n = blockIdx.x * 4 + wave;          // grid is exactly NN/4 blocks
    int j0 = row_ptr[n];
    int j1 = row_ptr[n + 1];
    int cb = lane * 4;
    float a0 = 0.f, a1 = 0.f, a2 = 0.f, a3 = 0.f;
    int j = j0;
    for (; j + 4 <= j1; j += 4) {
        int   c0 = csr_col[j],     c1 = csr_col[j + 1];
        int   c2 = csr_col[j + 2], c3 = csr_col[j + 3];
        float w0 = csr_val[j],     w1 = csr_val[j + 1];
        float w2 = csr_val[j + 2], w3 = csr_val[j + 3];
        ushort4 v0 = *(const ushort4*)&Vb[(size_t)c0 * KT + cb];
        ushort4 v1 = *(const ushort4*)&Vb[(size_t)c1 * KT + cb];
        ushort4 v2 = *(const ushort4*)&Vb[(size_t)c2 * KT + cb];
        ushort4 v3 = *(const ushort4*)&Vb[(size_t)c3 * KT + cb];
        a0 += w0 * bf2f(v0.x) + w1 * bf2f(v1.x) + w2 * bf2f(v2.x) + w3 * bf2f(v3.x);
        a1 += w0 * bf2f(v0.y) + w1 * bf2f(v1.y) + w2 * bf2f(v2.y) + w3 * bf2f(v3.y);
        a2 += w0 * bf2f(v0.z) + w1 * bf2f(v1.z) + w2 * bf2f(v2.z) + w3 * bf2f(v3.z);
        a3 += w0 * bf2f(v0.w) + w1 * bf2f(v1.w) + w2 * bf2f(v2.w) + w3 * bf2f(v3.w);
    }
    for (; j < j1; ++j) {
        int   col = csr_col[j];
        float w   = csr_val[j];
        ushort4 v = *(const ushort4*)&Vb[(size_t)col * KT + cb];
        a0 += w * bf2f(v.x); a1 += w * bf2f(v.y);
        a2 += w * bf2f(v.z); a3 += w * bf2f(v.w);
    }
    float r0, r1, r2, r3;
    if (use_sub) {
        ushort4 s = *(const ushort4*)&subb[(size_t)n * KT + cb];
        r0 = alpha * a0 - bf2f(s.x);
        r1 = alpha * a1 - bf2f(s.y);
        r2 = alpha * a2 - bf2f(s.z);
        r3 = alpha * a3 - bf2f(s.w);
    } else {
        r0 = alpha * a0; r1 = alpha * a1; r2 = alpha * a2; r3 = alpha * a3;
    }
    ushort4 h;
    h.x = f2bf(r0); h.y = f2bf(r1); h.z = f2bf(r2); h.w = f2bf(r3);
    *(ushort4*)&outb[(size_t)n * KT + cb] = h;
}

// ---------------- fused bf16 MFMA GEMM ----------------
// out[M=40000][256] = Abf[M][1280] @ WT^T + bias
// 128x128 tile / block, 4 waves, 4x4 mfma_16x16x32_bf16 each (64x64/wave).
// __launch_bounds__(256,3): 3 blocks/CU -> all 626 blocks co-resident (no tail).
// LDS granule XOR-swizzle -> wave64 ds_read_b128 is uniformly 2-way (free).
__global__ __launch_bounds__(256, 3)
void gemm_mfma(const bf16_t* __restrict__ Abf,  // [MPAD][KT]
               const bf16_t* __restrict__ WT,   // [256][KT]
               const float* __restrict__ bias,
               float* __restrict__ out) {
    __shared__ bf16_t smem[8192];   // 16 KB: As = [0,4096), Bs = [4096,8192) elements
    int tid = threadIdx.x;
    int w = tid >> 6, lane = tid & 63;
    int m0 = blockIdx.x * 128;
    int n0 = blockIdx.y * 128;
    int wm = w & 1, wn = w >> 1;
    int quad = lane >> 4, l16 = lane & 15;

    // staging source addresses: LDS granule gi = (w*4+j)*64 + lane, fixed per lane.
    const bf16_t* srcbase[4];
    for (int j = 0; j < 4; ++j) {
        int gi = (w * 4 + j) * 64 + lane;           // 0..1023
        int t  = (gi >= 512) ? gi - 512 : gi;       // granule within tile
        int m  = t >> 2;                            // tile row (A: m_local, B: n_local)
        int pg = t & 3;
        int g  = pg ^ ((m >> 1) & 3);               // logical k-granule for this slot
        srcbase[j] = (gi >= 512 ? WT + (size_t)(n0 + m) * KT
                                : Abf + (size_t)(m0 + m) * KT) + g * 8;
    }

    int arow = wm * 64 + l16;
    int brow = wn * 64 + l16;
    int aoff0 = (arow * 4 + (quad ^ ((arow >> 1) & 3))) * 8;
    int boff0 = 4096 + (brow * 4 + (quad ^ ((brow >> 1) & 3))) * 8;

    floatx4 acc[4][4] = {};

    for (int k0 = 0; k0 < KT; k0 += 32) {
        __syncthreads();   // previous iter's LDS reads done before overwrite
#pragma unroll
        for (int j = 0; j < 4; ++j)
            GLL16(srcbase[j] + k0, &smem[(w * 4 + j) * 512]);
        __syncthreads();

        short8 af[4], bfr[4];
#pragma unroll
        for (int mt = 0; mt < 4; ++mt) af[mt]  = *(const short8*)&smem[aoff0 + mt * 512];
#pragma unroll
        for (int nt = 0; nt < 4; ++nt) bfr[nt] = *(const short8*)&smem[boff0 + nt * 512];
#pragma unroll
        for (int mt = 0; mt < 4; ++mt)
#pragma unroll
            for (int nt = 0; nt < 4; ++nt)
                acc[mt][nt] = __builtin_amdgcn_mfma_f32_16x16x32_bf16(
                    af[mt], bfr[nt], acc[mt][nt], 0, 0, 0);
    }

    // epilogue: C/D layout col=lane&15, row=quad*4+reg  (m89-verified)
#pragma unroll
    for (int nt = 0; nt < 4; ++nt) {
        int n = n0 + wn * 64 + nt * 16 + l16;
        float bv = bias[n];
#pragma unroll
        for (int mt = 0; mt < 4; ++mt) {
            int mbase = m0 + wm * 64 + mt * 16 + quad * 4;
#pragma unroll
            for (int r = 0; r < 4; ++r) {
                int m = mbase + r;
                if (m < NN) out[(size_t)m * C + n] = acc[mt][nt][r] + bv;
            }
        }
    }
}

// ---------------- launch ----------------

extern "C" void kernel_launch(void* const* d_in, const int* in_sizes, int n_in,
                              void* d_out, int out_size, void* d_ws, size_t ws_size,
                              hipStream_t stream) {
    const float* x    = (const float*)d_in[0];
    const int*   ei   = (const int*)d_in[1];
    const float* ew   = (const float*)d_in[2];
    const float* W    = (const float*)d_in[3];   // [5][256][256]
    const float* bias = (const float*)d_in[4];
    float* out = (float*)d_out;

    char* p = (char*)d_ws;
    auto carve = [&](size_t bytes) {
        char* q = p;
        p += (bytes + 255) & ~(size_t)255;
        return q;
    };
    int*    deg     = (int*)   carve(NN * 4);
    int*    cnt     = (int*)   carve(NN * 4);
    int*    incl    = (int*)   carve(NN * 4);
    int*    bsum    = (int*)   carve(256 * 4);
    int*    row_ptr = (int*)   carve((NN + 1) * 4);
    int*    cursor  = (int*)   carve(NN * 4);
    int*    csr_col = (int*)   carve(NE * 4);
    float*  csr_val = (float*) carve(NE * 4);
    float*  dis     = (float*) carve(NN * 4);
    bf16_t* abf     = (bf16_t*)carve((size_t)MPAD * KT * 2);   // fused bf16 A (recursion state)
    bf16_t* WT      = (bf16_t*)carve((size_t)C * KT * 2);      // W transposed bf16
    (void)ws_size; (void)n_in; (void)in_sizes; (void)out_size;

    const int NB_E = (NE + 255) / 256;   // 1250
    const int NB_N = (NN + 255) / 256;   // 157

    hipMemsetAsync(deg, 0, NN * 4, stream);
    hipMemsetAsync(cnt, 0, NN * 4, stream);

    count_kernel<<<NB_E, 256, 0, stream>>>(ei, deg, cnt);
    dis_kernel<<<NB_N, 256, 0, stream>>>(deg, dis);
    scan1_kernel<<<NB_N, 256, 0, stream>>>(cnt, incl, bsum);
    scan2_kernel<<<1, 256, 0, stream>>>(bsum, NB_N);
    scan3_kernel<<<NB_N, 256, 0, stream>>>(cnt, incl, bsum, row_ptr, cursor);
    fill_kernel<<<NB_E, 256, 0, stream>>>(ei, ew, dis, cursor, csr_col, csr_val);

    convx_kernel<<<(NN * 64 + 255) / 256, 256, 0, stream>>>(x, abf);
    wt_kernel<<<(256 * KT + 255) / 256, 256, 0, stream>>>(W, WT);

    // Chebyshev recursion, bf16 state in abf chunks 0..4 (chunk k at abf + k*256)
    // tx1 = L x
    spmm_kernel<<<NN / 4, 256, 0, stream>>>(abf + 0 * 256, nullptr, row_ptr, csr_col,
                                            csr_val, abf + 1 * 256, 1.0f, 0);
    // tx2 = 2 L tx1 - tx0
    spmm_kernel<<<NN / 4, 256, 0, stream>>>(abf + 1 * 256, abf + 0 * 256, row_ptr,
                                            csr_col, csr_val, abf + 2 * 256, 2.0f, 1);
    // tx3 = 2 L tx2 - tx1
    spmm_kernel<<<NN / 4, 256, 0, stream>>>(abf + 2 * 256, abf + 1 * 256, row_ptr,
                                            csr_col, csr_val, abf + 3 * 256, 2.0f, 1);
    // tx4 = 2 L tx3 - tx2
    spmm_kernel<<<NN / 4, 256, 0, stream>>>(abf + 3 * 256, abf + 2 * 256, row_ptr,
                                            csr_col, csr_val, abf + 4 * 256, 2.0f, 1);

    // fused GEMM: out = abf @ WT^T + bias
    dim3 ggrid(313, 2);
    gemm_mfma<<<ggrid, 256, 0, stream>>>(abf, WT, bias, out);
}

// Round 5
// 318.482 us; speedup vs baseline: 2.3812x; 1.0227x over previous
//
#include <hip/hip_runtime.h>

#define NN 40000
#define NE 320000
#define C 256
#define KORD 5
#define KT 1280          // fused K = 5 * 256

typedef __attribute__((ext_vector_type(8))) short short8;   // 8 x bf16 (4 VGPR)
typedef __attribute__((ext_vector_type(4))) float floatx4;  // 4 x f32
typedef unsigned short bf16_t;

__device__ __forceinline__ bf16_t f2bf(float f) {
    union { float f; unsigned u; } v; v.f = f;
    unsigned r = v.u + 0x7fffu + ((v.u >> 16) & 1u);  // RTNE
    return (bf16_t)(r >> 16);
}
__device__ __forceinline__ float bf2f(bf16_t h) {
    union { unsigned u; float f; } v; v.u = ((unsigned)h) << 16;
    return v.f;
}

#define GLL16(gsrc, ldst)                                                        \
    __builtin_amdgcn_global_load_lds(                                            \
        (const __attribute__((address_space(1))) void*)(gsrc),                   \
        (__attribute__((address_space(3))) void*)(ldst), 16, 0, 0)

// ---------------- graph preprocessing ----------------

__global__ void count_kernel(const int* __restrict__ ei,
                             int* __restrict__ deg_keep,
                             int* __restrict__ cnt_all) {
    int e = blockIdx.x * 256 + threadIdx.x;
    if (e >= NE) return;
    int r = ei[e];
    int c = ei[NE + e];
    atomicAdd(&cnt_all[r], 1);
    if (r != c) atomicAdd(&deg_keep[r], 1);
}

__global__ void dis_kernel(const int* __restrict__ deg, float* __restrict__ dis) {
    int n = blockIdx.x * 256 + threadIdx.x;
    if (n >= NN) return;
    int d = deg[n];
    dis[n] = (d > 0) ? rsqrtf((float)d) : 0.0f;
}

__global__ void scan1_kernel(const int* __restrict__ cnt,
                             int* __restrict__ incl,
                             int* __restrict__ bsum) {
    __shared__ int s[256];
    int t = threadIdx.x;
    int idx = blockIdx.x * 256 + t;
    int v = (idx < NN) ? cnt[idx] : 0;
    s[t] = v;
    __syncthreads();
    for (int off = 1; off < 256; off <<= 1) {
        int add = (t >= off) ? s[t - off] : 0;
        __syncthreads();
        s[t] += add;
        __syncthreads();
    }
    if (idx < NN) incl[idx] = s[t];
    if (t == 255) bsum[blockIdx.x] = s[255];
}

__global__ void scan2_kernel(int* __restrict__ bsum, int nb) {
    __shared__ int s[256];
    int t = threadIdx.x;
    int v = (t < nb) ? bsum[t] : 0;
    s[t] = v;
    __syncthreads();
    for (int off = 1; off < 256; off <<= 1) {
        int add = (t >= off) ? s[t - off] : 0;
        __syncthreads();
        s[t] += add;
        __syncthreads();
    }
    if (t < nb) bsum[t] = s[t] - v;   // exclusive
}

__global__ void scan3_kernel(const int* __restrict__ cnt,
                             const int* __restrict__ incl,
                             const int* __restrict__ bexcl,
                             int* __restrict__ row_ptr,
                             int* __restrict__ cursor) {
    int idx = blockIdx.x * 256 + threadIdx.x;
    if (idx == 0) row_ptr[NN] = NE;
    if (idx >= NN) return;
    int rp = incl[idx] - cnt[idx] + bexcl[blockIdx.x];
    row_ptr[idx] = rp;
    cursor[idx]  = rp;
}

__global__ void fill_kernel(const int* __restrict__ ei,
                            const float* __restrict__ ew,
                            const float* __restrict__ dis,
                            int* __restrict__ cursor,
                            int* __restrict__ csr_col,
                            float* __restrict__ csr_val) {
    int e = blockIdx.x * 256 + threadIdx.x;
    if (e >= NE) return;
    int r = ei[e];
    int c = ei[NE + e];
    int pos = atomicAdd(&cursor[r], 1);
    float w = (r != c) ? ew[e] : 0.0f;     // removed self-loops -> weight 0
    csr_col[pos] = c;
    csr_val[pos] = -dis[r] * w * dis[c];
}

// convert x (fp32 [NN][256]) into bf16 A-chunk 0 of [NN][KT]
__global__ void convx_kernel(const float* __restrict__ x, bf16_t* __restrict__ abf) {
    int i = blockIdx.x * 256 + threadIdx.x;
    if (i >= NN * 64) return;
    int n = i >> 6, cg = i & 63;
    float4 f = *(const float4*)&x[(size_t)n * C + cg * 4];
    ushort4 h;
    h.x = f2bf(f.x); h.y = f2bf(f.y); h.z = f2bf(f.z); h.w = f2bf(f.w);
    *(ushort4*)&abf[(size_t)n * KT + cg * 4] = h;
}

// transpose+convert W[5][256][256] -> WT[n(256)][kt(1280)] bf16
__global__ void wt_kernel(const float* __restrict__ W, bf16_t* __restrict__ WT) {
    int t = blockIdx.x * 256 + threadIdx.x;
    if (t >= 256 * KT) return;
    int n = t & 255, kt = t >> 8;
    WT[(size_t)n * KT + kt] = f2bf(W[(size_t)kt * 256 + n]);
}

// ---------------- SpMM (bf16 state, unroll-8 MLP) ----------------
// outb[n][:] = bf16( alpha * sum_j val[j]*Vb[col[j]][:] - (use_sub ? subb[n][:] : 0) )
// One wave per node; unroll-by-8 gather -> 8 outstanding 512B row fetches.
__global__ __launch_bounds__(256)
void spmm_kernel(const bf16_t* __restrict__ Vb,
                 const bf16_t* __restrict__ subb,
                 const int* __restrict__ row_ptr,
                 const int* __restrict__ csr_col,
                 const float* __restrict__ csr_val,
                 bf16_t* __restrict__ outb,
                 float alpha, int use_sub) {
    int wave = __builtin_amdgcn_readfirstlane(threadIdx.x >> 6);  // wave-uniform
    int lane = threadIdx.x & 63;
    int n = blockIdx.x * 4 + wave;          // grid is exactly NN/4 blocks
    int j0 = row_ptr[n];
    int j1 = row_ptr[n + 1];
    int cb = lane * 4;
    float a0 = 0.f, a1 = 0.f, a2 = 0.f, a3 = 0.f;
    int j = j0;
    for (; j + 8 <= j1; j += 8) {
        int cc[8]; float ww[8]; ushort4 vv[8];
#pragma unroll
        for (int u = 0; u < 8; ++u) { cc[u] = csr_col[j + u]; ww[u] = csr_val[j + u]; }
#pragma unroll
        for (int u = 0; u < 8; ++u) vv[u] = *(const ushort4*)&Vb[(size_t)cc[u] * KT + cb];
#pragma unroll
        for (int u = 0; u < 8; ++u) {
            a0 += ww[u] * bf2f(vv[u].x); a1 += ww[u] * bf2f(vv[u].y);
            a2 += ww[u] * bf2f(vv[u].z); a3 += ww[u] * bf2f(vv[u].w);
        }
    }
    for (; j + 4 <= j1; j += 4) {
        int cc[4]; float ww[4]; ushort4 vv[4];
#pragma unroll
        for (int u = 0; u < 4; ++u) { cc[u] = csr_col[j + u]; ww[u] = csr_val[j + u]; }
#pragma unroll
        for (int u = 0; u < 4; ++u) vv[u] = *(const ushort4*)&Vb[(size_t)cc[u] * KT + cb];
#pragma unroll
        for (int u = 0; u < 4; ++u) {
            a0 += ww[u] * bf2f(vv[u].x); a1 += ww[u] * bf2f(vv[u].y);
            a2 += ww[u] * bf2f(vv[u].z); a3 += ww[u] * bf2f(vv[u].w);
        }
    }
    for (; j < j1; ++j) {
        int   col = csr_col[j];
        float w   = csr_val[j];
        ushort4 v = *(const ushort4*)&Vb[(size_t)col * KT + cb];
        a0 += w * bf2f(v.x); a1 += w * bf2f(v.y);
        a2 += w * bf2f(v.z); a3 += w * bf2f(v.w);
    }
    float r0, r1, r2, r3;
    if (use_sub) {
        ushort4 s = *(const ushort4*)&subb[(size_t)n * KT + cb];
        r0 = alpha * a0 - bf2f(s.x);
        r1 = alpha * a1 - bf2f(s.y);
        r2 = alpha * a2 - bf2f(s.z);
        r3 = alpha * a3 - bf2f(s.w);
    } else {
        r0 = alpha * a0; r1 = alpha * a1; r2 = alpha * a2; r3 = alpha * a3;
    }
    ushort4 h;
    h.x = f2bf(r0); h.y = f2bf(r1); h.z = f2bf(r2); h.w = f2bf(r3);
    *(ushort4*)&outb[(size_t)n * KT + cb] = h;
}

// ---------------- fused bf16 MFMA GEMM ----------------
// out[M=40000][256] = Abf[M][1280] @ WT^T + bias
// 64x128 tile / block -> grid (625,2)=1250 blocks (~4.9/CU, balanced).
// 4 waves, wave-tile 32x64 via 2x4 mfma_16x16x32_bf16. LDS 12 KB,
// granule XOR-swizzle -> wave64 ds_read_b128 uniformly 2-way (free).
__global__ __launch_bounds__(256, 4)
void gemm_mfma(const bf16_t* __restrict__ Abf,  // [NN][KT]
               const bf16_t* __restrict__ WT,   // [256][KT]
               const float* __restrict__ bias,
               float* __restrict__ out) {
    __shared__ bf16_t smem[6144];   // As = [0,2048) (64rx32k), Bs = [2048,6144) (128rx32k)
    int tid = threadIdx.x;
    int w = tid >> 6, lane = tid & 63;
    int m0 = blockIdx.x * 64;
    int n0 = blockIdx.y * 128;
    int wm = w & 1, wn = w >> 1;
    int quad = lane >> 4, l16 = lane & 15;

    // staging: 768 granules of 16B per K-iter; wave w call j covers
    // granules gi = (w*3+j)*64 + lane. gi<256 -> A slot, else B slot.
    const bf16_t* srcbase[3];
#pragma unroll
    for (int j = 0; j < 3; ++j) {
        int gi = (w * 3 + j) * 64 + lane;           // 0..767
        int isB = gi >= 256;
        int t  = isB ? gi - 256 : gi;
        int row = t >> 2;                           // A: 0..63, B: 0..127
        int pg = t & 3;
        int g  = pg ^ ((row >> 1) & 3);             // logical k-granule in this slot
        srcbase[j] = (isB ? WT + (size_t)(n0 + row) * KT
                          : Abf + (size_t)(m0 + row) * KT) + g * 8;
    }

    int arow = wm * 32 + l16;
    int brow = wn * 64 + l16;
    int aoff0 = (arow * 4 + (quad ^ ((arow >> 1) & 3))) * 8;
    int boff0 = 2048 + (brow * 4 + (quad ^ ((brow >> 1) & 3))) * 8;

    floatx4 acc[2][4] = {};

    for (int k0 = 0; k0 < KT; k0 += 32) {
        __syncthreads();   // previous iter's LDS reads done before overwrite
#pragma unroll
        for (int j = 0; j < 3; ++j)
            GLL16(srcbase[j] + k0, &smem[(w * 3 + j) * 512]);
        __syncthreads();

        short8 af[2], bfr[4];
        af[0] = *(const short8*)&smem[aoff0];
        af[1] = *(const short8*)&smem[aoff0 + 512];
#pragma unroll
        for (int nt = 0; nt < 4; ++nt) bfr[nt] = *(const short8*)&smem[boff0 + nt * 512];
#pragma unroll
        for (int mt = 0; mt < 2; ++mt)
#pragma unroll
            for (int nt = 0; nt < 4; ++nt)
                acc[mt][nt] = __builtin_amdgcn_mfma_f32_16x16x32_bf16(
                    af[mt], bfr[nt], acc[mt][nt], 0, 0, 0);
    }

    // epilogue: C/D layout col=lane&15, row=quad*4+reg  (m89-verified)
#pragma unroll
    for (int nt = 0; nt < 4; ++nt) {
        int n = n0 + wn * 64 + nt * 16 + l16;
        float bv = bias[n];
#pragma unroll
        for (int mt = 0; mt < 2; ++mt) {
            int mbase = m0 + wm * 32 + mt * 16 + quad * 4;
#pragma unroll
            for (int r = 0; r < 4; ++r)
                out[(size_t)(mbase + r) * C + n] = acc[mt][nt][r] + bv;
        }
    }
}

// ---------------- launch ----------------

extern "C" void kernel_launch(void* const* d_in, const int* in_sizes, int n_in,
                              void* d_out, int out_size, void* d_ws, size_t ws_size,
                              hipStream_t stream) {
    const float* x    = (const float*)d_in[0];
    const int*   ei   = (const int*)d_in[1];
    const float* ew   = (const float*)d_in[2];
    const float* W    = (const float*)d_in[3];   // [5][256][256]
    const float* bias = (const float*)d_in[4];
    float* out = (float*)d_out;

    char* p = (char*)d_ws;
    auto carve = [&](size_t bytes) {
        char* q = p;
        p += (bytes + 255) & ~(size_t)255;
        return q;
    };
    int*    deg     = (int*)   carve(NN * 4);
    int*    cnt     = (int*)   carve(NN * 4);
    int*    incl    = (int*)   carve(NN * 4);
    int*    bsum    = (int*)   carve(256 * 4);
    int*    row_ptr = (int*)   carve((NN + 1) * 4);
    int*    cursor  = (int*)   carve(NN * 4);
    int*    csr_col = (int*)   carve(NE * 4);
    float*  csr_val = (float*) carve(NE * 4);
    float*  dis     = (float*) carve(NN * 4);
    bf16_t* abf     = (bf16_t*)carve((size_t)NN * KT * 2);   // fused bf16 A (recursion state)
    bf16_t* WT      = (bf16_t*)carve((size_t)C * KT * 2);    // W transposed bf16
    (void)ws_size; (void)n_in; (void)in_sizes; (void)out_size;

    const int NB_E = (NE + 255) / 256;   // 1250
    const int NB_N = (NN + 255) / 256;   // 157

    hipMemsetAsync(deg, 0, NN * 4, stream);
    hipMemsetAsync(cnt, 0, NN * 4, stream);

    count_kernel<<<NB_E, 256, 0, stream>>>(ei, deg, cnt);
    dis_kernel<<<NB_N, 256, 0, stream>>>(deg, dis);
    scan1_kernel<<<NB_N, 256, 0, stream>>>(cnt, incl, bsum);
    scan2_kernel<<<1, 256, 0, stream>>>(bsum, NB_N);
    scan3_kernel<<<NB_N, 256, 0, stream>>>(cnt, incl, bsum, row_ptr, cursor);
    fill_kernel<<<NB_E, 256, 0, stream>>>(ei, ew, dis, cursor, csr_col, csr_val);

    convx_kernel<<<(NN * 64 + 255) / 256, 256, 0, stream>>>(x, abf);
    wt_kernel<<<(256 * KT + 255) / 256, 256, 0, stream>>>(W, WT);

    // Chebyshev recursion, bf16 state in abf chunks 0..4 (chunk k at abf + k*256)
    // tx1 = L x
    spmm_kernel<<<NN / 4, 256, 0, stream>>>(abf + 0 * 256, nullptr, row_ptr, csr_col,
                                            csr_val, abf + 1 * 256, 1.0f, 0);
    // tx2 = 2 L tx1 - tx0
    spmm_kernel<<<NN / 4, 256, 0, stream>>>(abf + 1 * 256, abf + 0 * 256, row_ptr,
                                            csr_col, csr_val, abf + 2 * 256, 2.0f, 1);
    // tx3 = 2 L tx2 - tx1
    spmm_kernel<<<NN / 4, 256, 0, stream>>>(abf + 2 * 256, abf + 1 * 256, row_ptr,
                                            csr_col, csr_val, abf + 3 * 256, 2.0f, 1);
    // tx4 = 2 L tx3 - tx2
    spmm_kernel<<<NN / 4, 256, 0, stream>>>(abf + 3 * 256, abf + 2 * 256, row_ptr,
                                            csr_col, csr_val, abf + 4 * 256, 2.0f, 1);

    // fused GEMM: out = abf @ WT^T + bias
    dim3 ggrid(625, 2);
    gemm_mfma<<<ggrid, 256, 0, stream>>>(abf, WT, bias, out);
}

// Round 6
// 307.187 us; speedup vs baseline: 2.4687x; 1.0368x over previous
//
#include <hip/hip_runtime.h>

#define NN 40000
#define NE 320000
#define C 256
#define KORD 5
#define KT 1280          // fused K = 5 * 256

typedef __attribute__((ext_vector_type(8))) short short8;   // 8 x bf16 (4 VGPR)
typedef __attribute__((ext_vector_type(4))) float floatx4;  // 4 x f32
typedef unsigned short bf16_t;

__device__ __forceinline__ bf16_t f2bf(float f) {
    union { float f; unsigned u; } v; v.f = f;
    unsigned r = v.u + 0x7fffu + ((v.u >> 16) & 1u);  // RTNE
    return (bf16_t)(r >> 16);
}
__device__ __forceinline__ float bf2f(bf16_t h) {
    union { unsigned u; float f; } v; v.u = ((unsigned)h) << 16;
    return v.f;
}

#define GLL16(gsrc, ldst)                                                        \
    __builtin_amdgcn_global_load_lds(                                            \
        (const __attribute__((address_space(1))) void*)(gsrc),                   \
        (__attribute__((address_space(3))) void*)(ldst), 16, 0, 0)

// ---------------- graph preprocessing ----------------

__global__ void count_kernel(const int* __restrict__ ei,
                             int* __restrict__ deg_keep,
                             int* __restrict__ cnt_all) {
    int e = blockIdx.x * 256 + threadIdx.x;
    if (e >= NE) return;
    int r = ei[e];
    int c = ei[NE + e];
    atomicAdd(&cnt_all[r], 1);
    if (r != c) atomicAdd(&deg_keep[r], 1);
}

__global__ void dis_kernel(const int* __restrict__ deg, float* __restrict__ dis) {
    int n = blockIdx.x * 256 + threadIdx.x;
    if (n >= NN) return;
    int d = deg[n];
    dis[n] = (d > 0) ? rsqrtf((float)d) : 0.0f;
}

__global__ void scan1_kernel(const int* __restrict__ cnt,
                             int* __restrict__ incl,
                             int* __restrict__ bsum) {
    __shared__ int s[256];
    int t = threadIdx.x;
    int idx = blockIdx.x * 256 + t;
    int v = (idx < NN) ? cnt[idx] : 0;
    s[t] = v;
    __syncthreads();
    for (int off = 1; off < 256; off <<= 1) {
        int add = (t >= off) ? s[t - off] : 0;
        __syncthreads();
        s[t] += add;
        __syncthreads();
    }
    if (idx < NN) incl[idx] = s[t];
    if (t == 255) bsum[blockIdx.x] = s[255];
}

__global__ void scan2_kernel(int* __restrict__ bsum, int nb) {
    __shared__ int s[256];
    int t = threadIdx.x;
    int v = (t < nb) ? bsum[t] : 0;
    s[t] = v;
    __syncthreads();
    for (int off = 1; off < 256; off <<= 1) {
        int add = (t >= off) ? s[t - off] : 0;
        __syncthreads();
        s[t] += add;
        __syncthreads();
    }
    if (t < nb) bsum[t] = s[t] - v;   // exclusive
}

__global__ void scan3_kernel(const int* __restrict__ cnt,
                             const int* __restrict__ incl,
                             const int* __restrict__ bexcl,
                             int* __restrict__ row_ptr,
                             int* __restrict__ cursor) {
    int idx = blockIdx.x * 256 + threadIdx.x;
    if (idx == 0) row_ptr[NN] = NE;
    if (idx >= NN) return;
    int rp = incl[idx] - cnt[idx] + bexcl[blockIdx.x];
    row_ptr[idx] = rp;
    cursor[idx]  = rp;
}

__global__ void fill_kernel(const int* __restrict__ ei,
                            const float* __restrict__ ew,
                            const float* __restrict__ dis,
                            int* __restrict__ cursor,
                            int* __restrict__ csr_col,
                            float* __restrict__ csr_val) {
    int e = blockIdx.x * 256 + threadIdx.x;
    if (e >= NE) return;
    int r = ei[e];
    int c = ei[NE + e];
    int pos = atomicAdd(&cursor[r], 1);
    float w = (r != c) ? ew[e] : 0.0f;     // removed self-loops -> weight 0
    csr_col[pos] = c;
    csr_val[pos] = -dis[r] * w * dis[c];
}

// convert x (fp32 [NN][256]) into bf16 A-chunk 0 of [NN][KT]
__global__ void convx_kernel(const float* __restrict__ x, bf16_t* __restrict__ abf) {
    int i = blockIdx.x * 256 + threadIdx.x;
    if (i >= NN * 64) return;
    int n = i >> 6, cg = i & 63;
    float4 f = *(const float4*)&x[(size_t)n * C + cg * 4];
    ushort4 h;
    h.x = f2bf(f.x); h.y = f2bf(f.y); h.z = f2bf(f.z); h.w = f2bf(f.w);
    *(ushort4*)&abf[(size_t)n * KT + cg * 4] = h;
}

// transpose+convert W[5][256][256] -> WT[n(256)][kt(1280)] bf16
__global__ void wt_kernel(const float* __restrict__ W, bf16_t* __restrict__ WT) {
    int t = blockIdx.x * 256 + threadIdx.x;
    if (t >= 256 * KT) return;
    int n = t & 255, kt = t >> 8;
    WT[(size_t)n * KT + kt] = f2bf(W[(size_t)kt * 256 + n]);
}

// ---------------- SpMM (bf16 state, unroll-8 MLP) ----------------
// outb[n][:] = bf16( alpha * sum_j val[j]*Vb[col[j]][:] - (use_sub ? subb[n][:] : 0) )
__global__ __launch_bounds__(256)
void spmm_kernel(const bf16_t* __restrict__ Vb,
                 const bf16_t* __restrict__ subb,
                 const int* __restrict__ row_ptr,
                 const int* __restrict__ csr_col,
                 const float* __restrict__ csr_val,
                 bf16_t* __restrict__ outb,
                 float alpha, int use_sub) {
    int wave = __builtin_amdgcn_readfirstlane(threadIdx.x >> 6);  // wave-uniform
    int lane = threadIdx.x & 63;
    int n = blockIdx.x * 4 + wave;          // grid is exactly NN/4 blocks
    int j0 = row_ptr[n];
    int j1 = row_ptr[n + 1];
    int cb = lane * 4;
    float a0 = 0.f, a1 = 0.f, a2 = 0.f, a3 = 0.f;
    int j = j0;
    for (; j + 8 <= j1; j += 8) {
        int cc[8]; float ww[8]; ushort4 vv[8];
#pragma unroll
        for (int u = 0; u < 8; ++u) { cc[u] = csr_col[j + u]; ww[u] = csr_val[j + u]; }
#pragma unroll
        for (int u = 0; u < 8; ++u) vv[u] = *(const ushort4*)&Vb[(size_t)cc[u] * KT + cb];
#pragma unroll
        for (int u = 0; u < 8; ++u) {
            a0 += ww[u] * bf2f(vv[u].x); a1 += ww[u] * bf2f(vv[u].y);
            a2 += ww[u] * bf2f(vv[u].z); a3 += ww[u] * bf2f(vv[u].w);
        }
    }
    for (; j + 4 <= j1; j += 4) {
        int cc[4]; float ww[4]; ushort4 vv[4];
#pragma unroll
        for (int u = 0; u < 4; ++u) { cc[u] = csr_col[j + u]; ww[u] = csr_val[j + u]; }
#pragma unroll
        for (int u = 0; u < 4; ++u) vv[u] = *(const ushort4*)&Vb[(size_t)cc[u] * KT + cb];
#pragma unroll
        for (int u = 0; u < 4; ++u) {
            a0 += ww[u] * bf2f(vv[u].x); a1 += ww[u] * bf2f(vv[u].y);
            a2 += ww[u] * bf2f(vv[u].z); a3 += ww[u] * bf2f(vv[u].w);
        }
    }
    for (; j < j1; ++j) {
        int   col = csr_col[j];
        float w   = csr_val[j];
        ushort4 v = *(const ushort4*)&Vb[(size_t)col * KT + cb];
        a0 += w * bf2f(v.x); a1 += w * bf2f(v.y);
        a2 += w * bf2f(v.z); a3 += w * bf2f(v.w);
    }
    float r0, r1, r2, r3;
    if (use_sub) {
        ushort4 s = *(const ushort4*)&subb[(size_t)n * KT + cb];
        r0 = alpha * a0 - bf2f(s.x);
        r1 = alpha * a1 - bf2f(s.y);
        r2 = alpha * a2 - bf2f(s.z);
        r3 = alpha * a3 - bf2f(s.w);
    } else {
        r0 = alpha * a0; r1 = alpha * a1; r2 = alpha * a2; r3 = alpha * a3;
    }
    ushort4 h;
    h.x = f2bf(r0); h.y = f2bf(r1); h.z = f2bf(r2); h.w = f2bf(r3);
    *(ushort4*)&outb[(size_t)n * KT + cb] = h;
}

// ---------------- fused bf16 MFMA GEMM ----------------
// out[M=40000][256] = Abf[M][1280] @ WT^T + bias
// 64x128 tile, BK=64 -> 20 K-iters (half the barriers of BK=32).
// grid (625,2)=1250 blocks; __launch_bounds__(256,5) -> capacity 1280, zero tail.
// LDS 24 KB: As [64r][8 granules], Bs [128r][8 granules], granule XOR-swizzle
// g^(row&7) -> wave64 ds_read_b128 uniformly 2-way (free per m136).
__global__ __launch_bounds__(256, 5)
void gemm_mfma(const bf16_t* __restrict__ Abf,  // [NN][KT]
               const bf16_t* __restrict__ WT,   // [256][KT]
               const float* __restrict__ bias,
               float* __restrict__ out) {
    __shared__ bf16_t smem[12288];  // As = [0,4096), Bs = [4096,12288) elements
    int tid = threadIdx.x;
    int w = tid >> 6, lane = tid & 63;
    int m0 = blockIdx.x * 64;
    int n0 = blockIdx.y * 128;
    int wm = w & 1, wn = w >> 1;
    int quad = lane >> 4, l16 = lane & 15, l7 = l16 & 7;

    // staging: 1536 granules of 16B per K-iter; wave w call j covers
    // granules gi = (w*6+j)*64 + lane. gi<512 -> A slot, else B slot.
    const bf16_t* srcbase[6];
#pragma unroll
    for (int j = 0; j < 6; ++j) {
        int gi = (w * 6 + j) * 64 + lane;           // 0..1535
        int isB = gi >= 512;
        int t  = isB ? gi - 512 : gi;
        int row = t >> 3;                           // A: 0..63, B: 0..127
        int pg = t & 7;
        int g  = pg ^ (row & 7);                    // physical k-granule slot
        srcbase[j] = (isB ? WT + (size_t)(n0 + row) * KT
                          : Abf + (size_t)(m0 + row) * KT) + g * 8;
    }

    int arowb = wm * 32 + l16;    // A fragment base row (mt adds 16)
    int browb = wn * 64 + l16;    // B fragment base row (nt adds 16)

    floatx4 acc[2][4] = {};

    for (int k0 = 0; k0 < KT; k0 += 64) {
        __syncthreads();   // previous iter's LDS reads done before overwrite
#pragma unroll
        for (int j = 0; j < 6; ++j)
            GLL16(srcbase[j] + k0, &smem[(w * 6 + j) * 512]);
        __syncthreads();

#pragma unroll
        for (int c = 0; c < 2; ++c) {              // two 32-k chunks inside BK=64
            int gp   = (c * 4 + quad) ^ l7;        // physical granule for this frag
            int aoff = (arowb * 8 + gp) * 8;
            int boff = 4096 + (browb * 8 + gp) * 8;
            short8 af[2], bfr[4];
#pragma unroll
            for (int mt = 0; mt < 2; ++mt) af[mt]  = *(const short8*)&smem[aoff + mt * 1024];
#pragma unroll
            for (int nt = 0; nt < 4; ++nt) bfr[nt] = *(const short8*)&smem[boff + nt * 1024];
#pragma unroll
            for (int mt = 0; mt < 2; ++mt)
#pragma unroll
                for (int nt = 0; nt < 4; ++nt)
                    acc[mt][nt] = __builtin_amdgcn_mfma_f32_16x16x32_bf16(
                        af[mt], bfr[nt], acc[mt][nt], 0, 0, 0);
        }
    }

    // epilogue: C/D layout col=lane&15, row=quad*4+reg  (m89-verified)
#pragma unroll
    for (int nt = 0; nt < 4; ++nt) {
        int n = n0 + wn * 64 + nt * 16 + l16;
        float bv = bias[n];
#pragma unroll
        for (int mt = 0; mt < 2; ++mt) {
            int mbase = m0 + wm * 32 + mt * 16 + quad * 4;
#pragma unroll
            for (int r = 0; r < 4; ++r)
                out[(size_t)(mbase + r) * C + n] = acc[mt][nt][r] + bv;
        }
    }
}

// ---------------- launch ----------------

extern "C" void kernel_launch(void* const* d_in, const int* in_sizes, int n_in,
                              void* d_out, int out_size, void* d_ws, size_t ws_size,
                              hipStream_t stream) {
    const float* x    = (const float*)d_in[0];
    const int*   ei   = (const int*)d_in[1];
    const float* ew   = (const float*)d_in[2];
    const float* W    = (const float*)d_in[3];   // [5][256][256]
    const float* bias = (const float*)d_in[4];
    float* out = (float*)d_out;

    char* p = (char*)d_ws;
    auto carve = [&](size_t bytes) {
        char* q = p;
        p += (bytes + 255) & ~(size_t)255;
        return q;
    };
    int*    deg     = (int*)   carve(NN * 4);
    int*    cnt     = (int*)   carve(NN * 4);
    int*    incl    = (int*)   carve(NN * 4);
    int*    bsum    = (int*)   carve(256 * 4);
    int*    row_ptr = (int*)   carve((NN + 1) * 4);
    int*    cursor  = (int*)   carve(NN * 4);
    int*    csr_col = (int*)   carve(NE * 4);
    float*  csr_val = (float*) carve(NE * 4);
    float*  dis     = (float*) carve(NN * 4);
    bf16_t* abf     = (bf16_t*)carve((size_t)NN * KT * 2);   // fused bf16 A (recursion state)
    bf16_t* WT      = (bf16_t*)carve((size_t)C * KT * 2);    // W transposed bf16
    (void)ws_size; (void)n_in; (void)in_sizes; (void)out_size;

    const int NB_E = (NE + 255) / 256;   // 1250
    const int NB_N = (NN + 255) / 256;   // 157

    hipMemsetAsync(deg, 0, NN * 4, stream);
    hipMemsetAsync(cnt, 0, NN * 4, stream);

    count_kernel<<<NB_E, 256, 0, stream>>>(ei, deg, cnt);
    dis_kernel<<<NB_N, 256, 0, stream>>>(deg, dis);
    scan1_kernel<<<NB_N, 256, 0, stream>>>(cnt, incl, bsum);
    scan2_kernel<<<1, 256, 0, stream>>>(bsum, NB_N);
    scan3_kernel<<<NB_N, 256, 0, stream>>>(cnt, incl, bsum, row_ptr, cursor);
    fill_kernel<<<NB_E, 256, 0, stream>>>(ei, ew, dis, cursor, csr_col, csr_val);

    convx_kernel<<<(NN * 64 + 255) / 256, 256, 0, stream>>>(x, abf);
    wt_kernel<<<(256 * KT + 255) / 256, 256, 0, stream>>>(W, WT);

    // Chebyshev recursion, bf16 state in abf chunks 0..4 (chunk k at abf + k*256)
    spmm_kernel<<<NN / 4, 256, 0, stream>>>(abf + 0 * 256, nullptr, row_ptr, csr_col,
                                            csr_val, abf + 1 * 256, 1.0f, 0);
    spmm_kernel<<<NN / 4, 256, 0, stream>>>(abf + 1 * 256, abf + 0 * 256, row_ptr,
                                            csr_col, csr_val, abf + 2 * 256, 2.0f, 1);
    spmm_kernel<<<NN / 4, 256, 0, stream>>>(abf + 2 * 256, abf + 1 * 256, row_ptr,
                                            csr_col, csr_val, abf + 3 * 256, 2.0f, 1);
    spmm_kernel<<<NN / 4, 256, 0, stream>>>(abf + 3 * 256, abf + 2 * 256, row_ptr,
                                            csr_col, csr_val, abf + 4 * 256, 2.0f, 1);

    // fused GEMM: out = abf @ WT^T + bias
    dim3 ggrid(625, 2);
    gemm_mfma<<<ggrid, 256, 0, stream>>>(abf, WT, bias, out);
}